// Round 5
// baseline (3076.592 us; speedup 1.0000x reference)
//
#include <hip/hip_runtime.h>
#include <hip/hip_bf16.h>
#include <cstdint>
#include <cstddef>

// Quantized SwiGLU MLP: out = (silu((x@wg^T)*sg) * ((x@wu^T)*su)) @ wd^T * sd
// x: [8192,4096] fp32; wg/wu: [11008,4096] int8 (delivered as int32);
// wd: [4096,11008] int8 (as int32).
// Strategy: exact int->bf16 weight expansion (scale in epilogue), x->bf16,
// m97-style 128-tile MFMA GEMMs with global_load_lds staging + chunk-XOR
// swizzle (linear LDS dest, inverse-swizzled global source, swizzled reads),
// T1 chunked XCD blockIdx swizzle.
// ws-ADAPTIVE: tokens processed in MT chunks (MT chosen from ws_size) and
// weights converted in N-chunks sized to the remaining scratch -> works for
// any ws_size >= ~12 MiB; identical schedule every call (graph-safe).
// MFMA 16x16x32 bf16 fragment: lane l holds row/col = l&15, k = (l>>4)*8+e
// (8 contiguous k) -> one ds_read_b128 per fragment.

#define HID 4096
#define INTER 11008
#define NTOK 8192

typedef __attribute__((ext_vector_type(4))) float f32x4;
typedef __attribute__((ext_vector_type(8))) short short8;

__device__ __forceinline__ unsigned short f2bf(float f) {
  unsigned u = __float_as_uint(f);
  u += 0x7FFFu + ((u >> 16) & 1u);   // RNE
  return (unsigned short)(u >> 16);
}

__device__ __forceinline__ void gload_lds16(const void* g, void* l) {
  __builtin_amdgcn_global_load_lds((const __attribute__((address_space(1))) unsigned*)g,
                                   (__attribute__((address_space(3))) unsigned*)l,
                                   16, 0, 0);
}

// chunked XCD swizzle; identity when grid not divisible by 8 (stays bijective)
__device__ __forceinline__ int xcd_swz(int bid, int nwg) {
  if (nwg & 7) return bid;
  return (bid & 7) * (nwg >> 3) + (bid >> 3);
}

// ---------------- x fp32 -> bf16 ----------------
__global__ void cast_x_k(const float4* __restrict__ xv, uint4* __restrict__ ov) {
  int i = blockIdx.x * 256 + threadIdx.x;   // 8 elems/thread
  float4 a = xv[2 * i], b = xv[2 * i + 1];
  uint4 o;
  o.x = (unsigned)f2bf(a.x) | ((unsigned)f2bf(a.y) << 16);
  o.y = (unsigned)f2bf(a.z) | ((unsigned)f2bf(a.w) << 16);
  o.z = (unsigned)f2bf(b.x) | ((unsigned)f2bf(b.y) << 16);
  o.w = (unsigned)f2bf(b.z) | ((unsigned)f2bf(b.w) << 16);
  ov[i] = o;
}

// ---------------- int32 (value in [-128,127]) -> bf16 exact ----------------
__device__ __forceinline__ unsigned pack2(int i0, int i1) {
  // ints |v|<=128 are exact in bf16: truncate fp32 bits
  return (__float_as_uint((float)i0) >> 16) | (__float_as_uint((float)i1) & 0xFFFF0000u);
}
__global__ void convw_k(const int4* __restrict__ w, uint4* __restrict__ o) {
  int i = blockIdx.x * 256 + threadIdx.x;   // 8 int32 -> 8 bf16 per thread
  int4 a = w[2 * i], b = w[2 * i + 1];
  uint4 r;
  r.x = pack2(a.x, a.y);
  r.y = pack2(a.z, a.w);
  r.z = pack2(b.x, b.y);
  r.w = pack2(b.z, b.w);
  o[i] = r;
}

// ---------------- fused gate+up GEMM + SwiGLU -> hidden bf16 ----------------
// 128x128 tile, BK=64, 4 waves of 64x64, dual accumulators. A = token chunk
// (nbm = 1<<bmShift row-panels); B = weight chunk of nbn panels at abs bn0.
__launch_bounds__(256, 2)
__global__ void gemm_gateup_k(const unsigned short* __restrict__ xb,
                              const unsigned short* __restrict__ wg,
                              const unsigned short* __restrict__ wu,
                              const float* __restrict__ sg,
                              const float* __restrict__ su,
                              unsigned short* __restrict__ hid,
                              int bn0, int bmShift) {
  __shared__ unsigned short sA[128 * 64];
  __shared__ unsigned short sG[128 * 64];
  __shared__ unsigned short sU[128 * 64];
  const int w = xcd_swz(blockIdx.x, gridDim.x);
  const int bm = w & ((1 << bmShift) - 1);   // fast: work-ids share weight panel
  const int bn = w >> bmShift;               // chunk-local panel
  const int tid = threadIdx.x;
  const int wid = tid >> 6;
  const int lane = tid & 63;
  const int wr = wid >> 1, wc = wid & 1;
  const int lr = lane & 15, g = lane >> 4;

  // staging: LDS dest linear, global source chunk = c ^ (row&7)  (rule #21)
  int aOff[4], bOff[4], ldsO[4];
#pragma unroll
  for (int i = 0; i < 4; ++i) {
    int o = i * 4096 + wid * 1024 + lane * 16;
    int r = o >> 7;                        // LDS row (128B rows = 64 bf16)
    int c = (o >> 4) & 7;                  // 16B chunk within row
    int gk = (c ^ (r & 7)) * 16;           // inverse-swizzled global chunk
    aOff[i] = (bm * 128 + r) * (HID * 2) + gk;
    bOff[i] = (bn * 128 + r) * (HID * 2) + gk;
    ldsO[i] = i * 4096 + wid * 1024;       // wave-uniform LDS base
  }

  // fragment read: one b128 at chunk (s*4+g) ^ (row&7); row&7 == lr&7
  const int xk = lr & 7;
  int cks[2];
#pragma unroll
  for (int s = 0; s < 2; ++s) cks[s] = ((s * 4 + g) ^ xk) * 16;
  int arow[4], brow[4];
#pragma unroll
  for (int t = 0; t < 4; ++t) {
    arow[t] = (wr * 64 + t * 16 + lr) * 128;
    brow[t] = (wc * 64 + t * 16 + lr) * 128;
  }

  f32x4 accg[4][4] = {};
  f32x4 accu[4][4] = {};
  const char* xc = (const char*)xb;
  const char* gc = (const char*)wg;
  const char* uc = (const char*)wu;
  const char* sAc = (const char*)sA;
  const char* sGc = (const char*)sG;
  const char* sUc = (const char*)sU;

  for (int kt = 0; kt < HID / 64; ++kt) {   // 64 K-steps
    __syncthreads();
    const int kb = kt * 128;
#pragma unroll
    for (int i = 0; i < 4; ++i) {
      gload_lds16(xc + aOff[i] + kb, (void*)((char*)sA + ldsO[i]));
      gload_lds16(gc + bOff[i] + kb, (void*)((char*)sG + ldsO[i]));
      gload_lds16(uc + bOff[i] + kb, (void*)((char*)sU + ldsO[i]));
    }
    __syncthreads();   // compiler emits vmcnt(0) drain before barrier
#pragma unroll
    for (int s = 0; s < 2; ++s) {
      short8 af[4], gf[4], uf[4];
#pragma unroll
      for (int t = 0; t < 4; ++t) af[t] = *(const short8*)(sAc + arow[t] + cks[s]);
#pragma unroll
      for (int t = 0; t < 4; ++t) {
        gf[t] = *(const short8*)(sGc + brow[t] + cks[s]);
        uf[t] = *(const short8*)(sUc + brow[t] + cks[s]);
      }
#pragma unroll
      for (int mi = 0; mi < 4; ++mi)
#pragma unroll
        for (int ni = 0; ni < 4; ++ni) {
          accg[mi][ni] = __builtin_amdgcn_mfma_f32_16x16x32_bf16(af[mi], gf[ni], accg[mi][ni], 0, 0, 0);
          accu[mi][ni] = __builtin_amdgcn_mfma_f32_16x16x32_bf16(af[mi], uf[ni], accu[mi][ni], 0, 0, 0);
        }
    }
  }

  // epilogue: scale, SwiGLU, bf16 store. C/D: col=lane&15, row=(lane>>4)*4+reg
  const int colb = (bn0 + bn) * 128 + wc * 64;
  const int rowb = bm * 128 + wr * 64;      // chunk-local token row
#pragma unroll
  for (int ni = 0; ni < 4; ++ni) {
    const int col = colb + ni * 16 + lr;
    const float sgv = sg[col], suv = su[col];
#pragma unroll
    for (int mi = 0; mi < 4; ++mi) {
      const int row0 = rowb + mi * 16 + g * 4;
#pragma unroll
      for (int r = 0; r < 4; ++r) {
        float gv = accg[mi][ni][r] * sgv;
        float uv = accu[mi][ni][r] * suv;
        float hv = gv / (1.0f + __expf(-gv)) * uv;   // silu(g)*u
        hid[(size_t)(row0 + r) * INTER + col] = f2bf(hv);
      }
    }
  }
}

// ---------------- down GEMM: hidden @ wd^T * sd -> out fp32 ----------------
// 128x128 tile, BK=64, 4 waves of 64x64 (m103: 128^2 = 912 TF > 128x256).
__launch_bounds__(256, 3)
__global__ void gemm_down_k(const unsigned short* __restrict__ hb,
                            const unsigned short* __restrict__ wd,
                            const float* __restrict__ sd,
                            float* __restrict__ out,
                            int bn0, int bmShift, int m0) {
  __shared__ unsigned short sA[128 * 64];
  __shared__ unsigned short sB[128 * 64];
  const int w = xcd_swz(blockIdx.x, gridDim.x);
  const int bm = w & ((1 << bmShift) - 1);
  const int bn = w >> bmShift;
  const int tid = threadIdx.x;
  const int wid = tid >> 6;
  const int lane = tid & 63;
  const int wr = wid >> 1, wc = wid & 1;
  const int lr = lane & 15, g = lane >> 4;

  int aOff[4], bOff[4], ldsO[4];
#pragma unroll
  for (int i = 0; i < 4; ++i) {
    int o = i * 4096 + wid * 1024 + lane * 16;
    int r = o >> 7;
    int c = (o >> 4) & 7;
    int gk = (c ^ (r & 7)) * 16;
    aOff[i] = (bm * 128 + r) * (INTER * 2) + gk;
    bOff[i] = (bn * 128 + r) * (INTER * 2) + gk;
    ldsO[i] = i * 4096 + wid * 1024;
  }
  const int xk = lr & 7;
  int cks[2];
#pragma unroll
  for (int s = 0; s < 2; ++s) cks[s] = ((s * 4 + g) ^ xk) * 16;
  int arow[4], brow[4];
#pragma unroll
  for (int t = 0; t < 4; ++t) {
    arow[t] = (wr * 64 + t * 16 + lr) * 128;
    brow[t] = (wc * 64 + t * 16 + lr) * 128;
  }

  f32x4 acc[4][4] = {};
  const char* ac = (const char*)hb;
  const char* bc = (const char*)wd;
  const char* sAc = (const char*)sA;
  const char* sBc = (const char*)sB;

  for (int kt = 0; kt < INTER / 64; ++kt) {   // 172 K-steps
    __syncthreads();
    const int kb = kt * 128;
#pragma unroll
    for (int i = 0; i < 4; ++i) {
      gload_lds16(ac + aOff[i] + kb, (void*)((char*)sA + ldsO[i]));
      gload_lds16(bc + bOff[i] + kb, (void*)((char*)sB + ldsO[i]));
    }
    __syncthreads();
#pragma unroll
    for (int s = 0; s < 2; ++s) {
      short8 af[4], bf[4];
#pragma unroll
      for (int t = 0; t < 4; ++t) af[t] = *(const short8*)(sAc + arow[t] + cks[s]);
#pragma unroll
      for (int t = 0; t < 4; ++t) bf[t] = *(const short8*)(sBc + brow[t] + cks[s]);
#pragma unroll
      for (int mi = 0; mi < 4; ++mi)
#pragma unroll
        for (int ni = 0; ni < 4; ++ni)
          acc[mi][ni] = __builtin_amdgcn_mfma_f32_16x16x32_bf16(af[mi], bf[ni], acc[mi][ni], 0, 0, 0);
    }
  }

  const int colb = (bn0 + bn) * 128 + wc * 64;
  const int rowb = bm * 128 + wr * 64;
#pragma unroll
  for (int ni = 0; ni < 4; ++ni) {
    const int col = colb + ni * 16 + lr;
    const float sdv = sd[col];
#pragma unroll
    for (int mi = 0; mi < 4; ++mi) {
      const int row0 = rowb + mi * 16 + g * 4;
#pragma unroll
      for (int r = 0; r < 4; ++r)
        out[(size_t)(m0 + row0 + r) * HID + col] = acc[mi][ni][r] * sdv;
    }
  }
}

extern "C" void kernel_launch(void* const* d_in, const int* in_sizes, int n_in,
                              void* d_out, int out_size, void* d_ws, size_t ws_size,
                              hipStream_t stream) {
  const float* x = (const float*)d_in[0];
  const int* wg8 = (const int*)d_in[1];   // int8 values delivered as int32
  const float* sg = (const float*)d_in[2];
  const int* wu8 = (const int*)d_in[3];
  const float* su = (const float*)d_in[4];
  const int* wd8 = (const int*)d_in[5];
  const float* sd = (const float*)d_in[6];
  float* out = (float*)d_out;
  (void)in_sizes; (void)n_in; (void)out_size;

  // Pick token-chunking MT (1,2,..,64) so x_chunk+hid_chunk+8MiB fits in ws.
  int MT = 1;
  size_t xb_c = 0, hid_c = 0, woff = 0;
  for (;; MT <<= 1) {
    const int McTry = NTOK / MT;
    xb_c = (size_t)McTry * HID * 2;
    hid_c = (size_t)McTry * INTER * 2;
    woff = xb_c + hid_c;
    if (woff + (size_t)8 * 1024 * 1024 <= ws_size || MT == 64) break;
  }
  const int Mc = NTOK / MT;            // tokens per chunk (>=128)
  const int nbm = Mc / 128;            // row-panels per chunk (power of 2)
  int bmShift = 0;
  while ((1 << bmShift) < nbm) ++bmShift;

  char* ws = (char*)d_ws;
  unsigned short* xb  = (unsigned short*)(ws);
  unsigned short* hid = (unsigned short*)(ws + xb_c);
  const size_t cap = (ws_size > woff) ? (ws_size - woff) : 0;

  // weight-chunk sizes from remaining scratch
  const size_t PANEL_GU = (size_t)128 * HID * 2;    // 1 MiB per panel per matrix
  const size_t PANEL_DN = (size_t)128 * INTER * 2;  // 2.69 MiB per panel
  int cn = (int)(cap / (2 * PANEL_GU));
  if (cn < 1) cn = 1;
  if (cn > 86) cn = 86;
  int cnd = (int)(cap / PANEL_DN);
  if (cnd < 1) cnd = 1;
  if (cnd > 32) cnd = 32;
  unsigned short* wgb = (unsigned short*)(ws + woff);
  unsigned short* wub = wgb + (size_t)cn * 128 * HID;
  unsigned short* wdb = (unsigned short*)(ws + woff);   // reused after gate/up

  for (int mc = 0; mc < MT; ++mc) {
    const int m0 = mc * Mc;
    cast_x_k<<<Mc * 2, 256, 0, stream>>>((const float4*)(x + (size_t)m0 * HID), (uint4*)xb);

    // gate/up: 86 weight panels of 128 rows, K = HID
    for (int c0 = 0; c0 < 86; c0 += cn) {
      const int nbn = (86 - c0 < cn) ? (86 - c0) : cn;
      convw_k<<<nbn * 256, 256, 0, stream>>>((const int4*)(wg8 + (size_t)c0 * 128 * HID), (uint4*)wgb);
      convw_k<<<nbn * 256, 256, 0, stream>>>((const int4*)(wu8 + (size_t)c0 * 128 * HID), (uint4*)wub);
      gemm_gateup_k<<<nbm * nbn, 256, 0, stream>>>(xb, wgb, wub, sg, su, hid, c0, bmShift);
    }
    // down: 32 weight panels of 128 rows, K = INTER
    for (int c0 = 0; c0 < 32; c0 += cnd) {
      const int nbn = (32 - c0 < cnd) ? (32 - c0) : cnd;
      convw_k<<<nbn * 688, 256, 0, stream>>>((const int4*)(wd8 + (size_t)c0 * 128 * INTER), (uint4*)wdb);
      gemm_down_k<<<nbm * nbn, 256, 0, stream>>>(hid, wdb, sd, out, c0, bmShift, m0);
    }
  }
}